// Round 1
// baseline (1924.607 us; speedup 1.0000x reference)
//
#include <hip/hip_runtime.h>
#include <hip/hip_bf16.h>

#define MPTS 200000
#define NCAM 6
#define CIMG 96
#define HF 32
#define WF 88
#define PDIM 128
#define FDIM 224
#define ORIH 256
#define ORIW 704
#define GZD 32
#define GYD 512
#define GXD 448
#define NCELLS (GZD*GYD*GXD)
#define PAIR_CAP 16384
#define BN_EPS 1e-5f

// ---- workspace layout (bytes), all offsets 16B-aligned ----
#define OFF_GRID   0UL            // int[NCELLS]            29,360,128 B
#define OFF_IMGT   29360128UL     // float[6*32*88*96]       6,488,064 B
#define OFF_PROJ   35848192UL     // float[M*12]             9,600,000 B
#define OFF_FUSE   45448192UL     // bf16[M*224]            89,600,000 B
#define OFF_CNT    135048192UL    // int[32]
#define OFF_PAIRS  135048320UL    // int2[27*PAIR_CAP]       3,538,944 B
// total ~138.6 MB

// ---------------- scatter: grid[cell] = max point index (== last-write-wins) ----
__global__ __launch_bounds__(256) void k_scatter(const int* __restrict__ vc,
                                                 int* __restrict__ grid) {
    int i = blockIdx.x * 256 + threadIdx.x;
    if (i >= MPTS) return;
    int cz = vc[i*4+1], cy = vc[i*4+2], cx = vc[i*4+3];
    atomicMax(&grid[(cz*GYD + cy)*GXD + cx], i);
}

// ---------------- transpose img (cam,C,H,W) -> (cam,H,W,C) for coalesced gathers
__global__ __launch_bounds__(256) void k_transpose(const float* __restrict__ img,
                                                   float* __restrict__ imgt) {
    int tid = blockIdx.x * 256 + threadIdx.x;
    if (tid >= NCAM*CIMG*HF*WF) return;
    int c = tid % CIMG;
    int r = tid / CIMG;
    int x = r % WF;
    int r2 = r / WF;
    int y = r2 % HF;
    int cam = r2 / HF;
    imgt[tid] = img[((cam*CIMG + c)*HF + y)*WF + x];
}

// ---------------- per (point,cam) projection -> feature-map pixel coords ------
__global__ __launch_bounds__(256) void k_proj(const int* __restrict__ vc,
                                              const float* __restrict__ l2i,
                                              const float* __restrict__ iaug,
                                              const float* __restrict__ laug,
                                              float* __restrict__ proj) {
    int i = blockIdx.x * 256 + threadIdx.x;
    if (i >= MPTS) return;
    float cxf = (float)vc[i*4+3], cyf = (float)vc[i*4+2], czf = (float)vc[i*4+1];
    // lidar_aug inverse (3x3 adjugate)
    float a00=laug[0],a01=laug[1],a02=laug[2];
    float a10=laug[4],a11=laug[5],a12=laug[6];
    float a20=laug[8],a21=laug[9],a22=laug[10];
    float t0=laug[3], t1=laug[7], t2=laug[11];
    float det = a00*(a11*a22-a12*a21) - a01*(a10*a22-a12*a20) + a02*(a10*a21-a11*a20);
    float id = 1.0f/det;
    float b00 =  (a11*a22-a12*a21)*id, b01 = -(a01*a22-a02*a21)*id, b02 =  (a01*a12-a02*a11)*id;
    float b10 = -(a10*a22-a12*a20)*id, b11 =  (a00*a22-a02*a20)*id, b12 = -(a00*a12-a02*a10)*id;
    float b20 =  (a10*a21-a11*a20)*id, b21 = -(a00*a21-a01*a20)*id, b22 =  (a00*a11-a01*a10)*id;
    float px = cxf-t0, py = cyf-t1, pz = czf-t2;
    float X = b00*px + b01*py + b02*pz;
    float Y = b10*px + b11*py + b12*pz;
    float Z = b20*px + b21*py + b22*pz;
    #pragma unroll
    for (int cam = 0; cam < NCAM; cam++) {
        const float* Lm = l2i + cam*16;
        float c0 = Lm[0]*X + Lm[1]*Y + Lm[2]*Z  + Lm[3];
        float c1 = Lm[4]*X + Lm[5]*Y + Lm[6]*Z  + Lm[7];
        float c2 = Lm[8]*X + Lm[9]*Y + Lm[10]*Z + Lm[11];
        float z  = fminf(fmaxf(c2, 1e-5f), 100000.0f);
        float vx = c0/z, vy = c1/z, vz = z;
        const float* Am = iaug + cam*16;
        float d0 = Am[0]*vx + Am[1]*vy + Am[2]*vz + Am[3];
        float d1 = Am[4]*vx + Am[5]*vy + Am[6]*vz + Am[7];
        // x = ((d0/ORIW - .5)*2 + 1)*.5*(WF-1) == d0*(WF-1)/ORIW
        proj[i*12 + cam*2 + 0] = d0 * ((float)(WF-1)/(float)ORIW);
        proj[i*12 + cam*2 + 1] = d1 * ((float)(HF-1)/(float)ORIH);
    }
}

// ---------------- fuse = [pts_features | sum_cam bilinear(img)] as bf16 -------
__global__ __launch_bounds__(256) void k_fuse(const float* __restrict__ pts,
                                              const float* __restrict__ imgt,
                                              const float* __restrict__ proj,
                                              __hip_bfloat16* __restrict__ fuse) {
    int tid = blockIdx.x * 256 + threadIdx.x;
    if (tid >= MPTS*FDIM) return;
    int i = tid / FDIM;
    int c = tid % FDIM;
    float v;
    if (c < PDIM) {
        v = pts[i*PDIM + c];
    } else {
        int sc = c - PDIM;
        float s = 0.f;
        #pragma unroll
        for (int cam = 0; cam < NCAM; cam++) {
            float x = proj[i*12 + cam*2 + 0];
            float y = proj[i*12 + cam*2 + 1];
            // outside (-1, WF) x (-1, HF): all corner contributions are exactly 0
            if (x <= -1.0f || x >= (float)WF || y <= -1.0f || y >= (float)HF) continue;
            float x0f = floorf(x), y0f = floorf(y);
            int x0 = (int)x0f, y0 = (int)y0f;
            float wx1 = x - x0f, wy1 = y - y0f;
            float wx0 = 1.f - wx1, wy0 = 1.f - wy1;
            bool vx0 = (x0 >= 0) && (x0 <= WF-1);
            bool vx1 = (x0+1 >= 0) && (x0+1 <= WF-1);
            bool vy0 = (y0 >= 0) && (y0 <= HF-1);
            bool vy1 = (y0+1 >= 0) && (y0+1 <= HF-1);
            const float* base = imgt + (cam*HF*WF)*CIMG;
            if (vx0 && vy0) s += base[(y0*WF + x0)*CIMG + sc]     * (wx0*wy0);
            if (vx1 && vy0) s += base[(y0*WF + x0+1)*CIMG + sc]   * (wx1*wy0);
            if (vx0 && vy1) s += base[((y0+1)*WF + x0)*CIMG + sc] * (wx0*wy1);
            if (vx1 && vy1) s += base[((y0+1)*WF + x0+1)*CIMG + sc] * (wx1*wy1);
        }
        v = s;
    }
    fuse[i*FDIM + c] = __float2bfloat16(v);
}

// ---------------- build k-major pair lists for the 26 off-center offsets ------
__global__ __launch_bounds__(256) void k_pairs(const int* __restrict__ vc,
                                               const int* __restrict__ grid,
                                               int* __restrict__ cnt,
                                               int2* __restrict__ pairs) {
    int i = blockIdx.x * 256 + threadIdx.x;
    if (i >= MPTS) return;
    int cz = vc[i*4+1], cy = vc[i*4+2], cx = vc[i*4+3];
    #pragma unroll
    for (int k = 0; k < 27; k++) {
        if (k == 13) continue;
        int dz = k/9 - 1, dy = (k/3)%3 - 1, dx = k%3 - 1;
        int nz = cz+dz, ny = cy+dy, nx = cx+dx;
        if (nz < 0 || nz >= GZD || ny < 0 || ny >= GYD || nx < 0 || nx >= GXD) continue;
        int nid = grid[(nz*GYD + ny)*GXD + nx];
        if (nid < 0) continue;
        int slot = atomicAdd(&cnt[k], 1);
        if (slot < PAIR_CAP) pairs[k*PAIR_CAP + slot] = make_int2(i, nid);
    }
}

// ---- shared micro-kernel: 32 rows x 224 K x 128 cols, thread = (col, col+64) x 8 rows
__device__ __forceinline__ void gemm_tile(const float (*s_f)[FDIM],
                                          const float* __restrict__ Wk,
                                          int col, int pg,
                                          float* acc0, float* acc1) {
    for (int c0 = 0; c0 < FDIM; c0 += 8) {
        float w0[8], w1[8];
        #pragma unroll
        for (int cc = 0; cc < 8; cc++) {
            w0[cc] = Wk[(c0+cc)*PDIM + col];
            w1[cc] = Wk[(c0+cc)*PDIM + col + 64];
        }
        #pragma unroll
        for (int p = 0; p < 8; p++) {
            const float4* f4 = reinterpret_cast<const float4*>(&s_f[pg*8+p][c0]);
            float4 fa = f4[0], fb = f4[1];
            acc0[p] += fa.x*w0[0]+fa.y*w0[1]+fa.z*w0[2]+fa.w*w0[3]
                     + fb.x*w0[4]+fb.y*w0[5]+fb.z*w0[6]+fb.w*w0[7];
            acc1[p] += fa.x*w1[0]+fa.y*w1[1]+fa.z*w1[2]+fa.w*w1[3]
                     + fb.x*w1[4]+fb.y*w1[5]+fb.z*w1[6]+fb.w*w1[7];
        }
    }
}

// ---------------- neighbor GEMMs: per (k, 32-pair tile), atomic scatter-add ----
__global__ __launch_bounds__(256) void k_nbr(const int2* __restrict__ pairs,
                                             const int* __restrict__ cnt,
                                             const __hip_bfloat16* __restrict__ fuse,
                                             const float* __restrict__ W,
                                             float* __restrict__ out) {
    int k = blockIdx.y;
    if (k >= 13) k += 1;                    // skip center
    int n = cnt[k];
    if (n > PAIR_CAP) n = PAIR_CAP;
    int p0 = blockIdx.x * 32;
    if (p0 >= n) return;
    int nn = min(32, n - p0);

    __shared__ int s_i[32];
    __shared__ int s_j[32];
    __shared__ float s_f[32][FDIM];
    int tid = threadIdx.x;
    if (tid < 32) {
        if (tid < nn) { int2 pr = pairs[k*PAIR_CAP + p0 + tid]; s_i[tid] = pr.x; s_j[tid] = pr.y; }
        else          { s_i[tid] = -1; s_j[tid] = -1; }
    }
    __syncthreads();
    for (int idx = tid; idx < 32*FDIM; idx += 256) {
        int r = idx / FDIM, c = idx % FDIM;
        int j = s_j[r];
        s_f[r][c] = (j >= 0) ? __bfloat162float(fuse[j*FDIM + c]) : 0.f;
    }
    __syncthreads();

    int col = tid & 63;
    int pg  = tid >> 6;
    const float* Wk = W + k*FDIM*PDIM;
    float acc0[8], acc1[8];
    #pragma unroll
    for (int p = 0; p < 8; p++) { acc0[p] = 0.f; acc1[p] = 0.f; }
    gemm_tile(s_f, Wk, col, pg, acc0, acc1);

    #pragma unroll
    for (int p = 0; p < 8; p++) {
        int pr = pg*8 + p;
        int ii = s_i[pr];
        if (ii >= 0) {
            unsafeAtomicAdd(&out[ii*PDIM + col],      acc0[p]);
            unsafeAtomicAdd(&out[ii*PDIM + col + 64], acc1[p]);
        }
    }
}

// ---------------- center GEMM (k=13, all points) + BN + ReLU epilogue ---------
__global__ __launch_bounds__(256) void k_center(const int* __restrict__ vc,
                                                const int* __restrict__ grid,
                                                const __hip_bfloat16* __restrict__ fuse,
                                                const float* __restrict__ W,
                                                const float* __restrict__ gamma,
                                                const float* __restrict__ beta,
                                                const float* __restrict__ mean,
                                                const float* __restrict__ var,
                                                float* __restrict__ out) {
    int i0 = blockIdx.x * 32;
    __shared__ int s_j[32];
    __shared__ float s_f[32][FDIM];
    int tid = threadIdx.x;
    if (tid < 32) {
        int i = i0 + tid;
        int nid = -1;
        if (i < MPTS) {
            int cz = vc[i*4+1], cy = vc[i*4+2], cx = vc[i*4+3];
            nid = grid[(cz*GYD + cy)*GXD + cx];   // may be a duplicate's index
        }
        s_j[tid] = nid;
    }
    __syncthreads();
    for (int idx = tid; idx < 32*FDIM; idx += 256) {
        int r = idx / FDIM, c = idx % FDIM;
        int j = s_j[r];
        s_f[r][c] = (j >= 0) ? __bfloat162float(fuse[j*FDIM + c]) : 0.f;
    }
    __syncthreads();

    int col = tid & 63;
    int pg  = tid >> 6;
    const float* Wk = W + 13*FDIM*PDIM;
    float acc0[8], acc1[8];
    #pragma unroll
    for (int p = 0; p < 8; p++) { acc0[p] = 0.f; acc1[p] = 0.f; }
    gemm_tile(s_f, Wk, col, pg, acc0, acc1);

    float g0 = gamma[col],    b0 = beta[col],    m0 = mean[col],    r0 = rsqrtf(var[col]+BN_EPS);
    float g1 = gamma[col+64], b1 = beta[col+64], m1 = mean[col+64], r1 = rsqrtf(var[col+64]+BN_EPS);
    #pragma unroll
    for (int p = 0; p < 8; p++) {
        int i = i0 + pg*8 + p;
        if (i < MPTS) {
            int o = i*PDIM + col;
            float v0 = out[o] + acc0[p];            // neighbor atomics already landed
            v0 = (v0 - m0)*r0*g0 + b0;
            out[o] = fmaxf(v0, 0.f);
            float v1 = out[o+64] + acc1[p];
            v1 = (v1 - m1)*r1*g1 + b1;
            out[o+64] = fmaxf(v1, 0.f);
        }
    }
}

extern "C" void kernel_launch(void* const* d_in, const int* in_sizes, int n_in,
                              void* d_out, int out_size, void* d_ws, size_t ws_size,
                              hipStream_t stream) {
    const float* pts   = (const float*)d_in[0];
    const int*   vc    = (const int*)d_in[1];
    const float* img   = (const float*)d_in[2];
    const float* l2i   = (const float*)d_in[3];
    const float* iaug  = (const float*)d_in[4];
    const float* laug  = (const float*)d_in[5];
    const float* conv  = (const float*)d_in[6];
    const float* gamma = (const float*)d_in[7];
    const float* beta  = (const float*)d_in[8];
    const float* mean  = (const float*)d_in[9];
    const float* var   = (const float*)d_in[10];
    float* out = (float*)d_out;

    char* ws = (char*)d_ws;
    int*            grid  = (int*)(ws + OFF_GRID);
    float*          imgt  = (float*)(ws + OFF_IMGT);
    float*          proj  = (float*)(ws + OFF_PROJ);
    __hip_bfloat16* fuse  = (__hip_bfloat16*)(ws + OFF_FUSE);
    int*            cnt   = (int*)(ws + OFF_CNT);
    int2*           pairs = (int2*)(ws + OFF_PAIRS);

    hipMemsetAsync(grid, 0xFF, (size_t)NCELLS*4, stream);          // grid = -1
    hipMemsetAsync(cnt, 0, 32*4, stream);
    hipMemsetAsync(d_out, 0, (size_t)out_size*4, stream);          // atomic accum base

    int blocksM = (MPTS + 255)/256;
    k_scatter<<<blocksM, 256, 0, stream>>>(vc, grid);
    k_transpose<<<(NCAM*CIMG*HF*WF + 255)/256, 256, 0, stream>>>(img, imgt);
    k_proj<<<blocksM, 256, 0, stream>>>(vc, l2i, iaug, laug, proj);
    k_fuse<<<(MPTS*FDIM)/256, 256, 0, stream>>>(pts, imgt, proj, fuse);
    k_pairs<<<blocksM, 256, 0, stream>>>(vc, grid, cnt, pairs);
    k_nbr<<<dim3(PAIR_CAP/32, 26), 256, 0, stream>>>(pairs, cnt, fuse, conv, out);
    k_center<<<(MPTS + 31)/32, 256, 0, stream>>>(vc, grid, fuse, conv,
                                                 gamma, beta, mean, var, out);
}

// Round 2
// 935.898 us; speedup vs baseline: 2.0564x; 2.0564x over previous
//
#include <hip/hip_runtime.h>
#include <hip/hip_bf16.h>

#define MPTS 200000
#define NCAM 6
#define CIMG 96
#define HF 32
#define WF 88
#define PDIM 128
#define FDIM 224
#define ORIH 256
#define ORIW 704
#define GZD 32
#define GYD 512
#define GXD 448
#define NCELLS (GZD*GYD*GXD)
#define PAIR_CAP 16384
#define BN_EPS 1e-5f

// ---- workspace layout (bytes), all offsets 16B-aligned ----
#define OFF_GRID   0UL            // int[NCELLS]            29,360,128 B
#define OFF_IMGT   29360128UL     // float[6*32*88*96]       6,488,064 B
#define OFF_PROJ   35848192UL     // float[M*12]             9,600,000 B
#define OFF_FUSE   45448192UL     // bf16[M*224]            89,600,000 B
#define OFF_CNT    135048192UL    // int[32]
#define OFF_PAIRS  135048320UL    // int2[27*PAIR_CAP]       3,538,944 B

__device__ __forceinline__ float bf16bits_to_f32(unsigned short u) {
    return __uint_as_float(((unsigned int)u) << 16);
}
__device__ __forceinline__ unsigned short f32_to_bf16bits(float f) {
    __hip_bfloat16 h = __float2bfloat16(f);   // RNE
    return *reinterpret_cast<unsigned short*>(&h);
}

// ---------------- scatter: grid[cell] = max point index (== last-write-wins) ----
__global__ __launch_bounds__(256) void k_scatter(const int* __restrict__ vc,
                                                 int* __restrict__ grid) {
    int i = blockIdx.x * 256 + threadIdx.x;
    if (i >= MPTS) return;
    int cz = vc[i*4+1], cy = vc[i*4+2], cx = vc[i*4+3];
    atomicMax(&grid[(cz*GYD + cy)*GXD + cx], i);
}

// ---------------- transpose img (cam,C,H,W) -> (cam,H,W,C) for coalesced gathers
__global__ __launch_bounds__(256) void k_transpose(const float* __restrict__ img,
                                                   float* __restrict__ imgt) {
    int tid = blockIdx.x * 256 + threadIdx.x;
    if (tid >= NCAM*CIMG*HF*WF) return;
    int c = tid % CIMG;
    int r = tid / CIMG;
    int x = r % WF;
    int r2 = r / WF;
    int y = r2 % HF;
    int cam = r2 / HF;
    imgt[tid] = img[((cam*CIMG + c)*HF + y)*WF + x];
}

// ---------------- per (point,cam) projection -> feature-map pixel coords ------
__global__ __launch_bounds__(256) void k_proj(const int* __restrict__ vc,
                                              const float* __restrict__ l2i,
                                              const float* __restrict__ iaug,
                                              const float* __restrict__ laug,
                                              float* __restrict__ proj) {
    int i = blockIdx.x * 256 + threadIdx.x;
    if (i >= MPTS) return;
    float cxf = (float)vc[i*4+3], cyf = (float)vc[i*4+2], czf = (float)vc[i*4+1];
    float a00=laug[0],a01=laug[1],a02=laug[2];
    float a10=laug[4],a11=laug[5],a12=laug[6];
    float a20=laug[8],a21=laug[9],a22=laug[10];
    float t0=laug[3], t1=laug[7], t2=laug[11];
    float det = a00*(a11*a22-a12*a21) - a01*(a10*a22-a12*a20) + a02*(a10*a21-a11*a20);
    float id = 1.0f/det;
    float b00 =  (a11*a22-a12*a21)*id, b01 = -(a01*a22-a02*a21)*id, b02 =  (a01*a12-a02*a11)*id;
    float b10 = -(a10*a22-a12*a20)*id, b11 =  (a00*a22-a02*a20)*id, b12 = -(a00*a12-a02*a10)*id;
    float b20 =  (a10*a21-a11*a20)*id, b21 = -(a00*a21-a01*a20)*id, b22 =  (a00*a11-a01*a10)*id;
    float px = cxf-t0, py = cyf-t1, pz = czf-t2;
    float X = b00*px + b01*py + b02*pz;
    float Y = b10*px + b11*py + b12*pz;
    float Z = b20*px + b21*py + b22*pz;
    #pragma unroll
    for (int cam = 0; cam < NCAM; cam++) {
        const float* Lm = l2i + cam*16;
        float c0 = Lm[0]*X + Lm[1]*Y + Lm[2]*Z  + Lm[3];
        float c1 = Lm[4]*X + Lm[5]*Y + Lm[6]*Z  + Lm[7];
        float c2 = Lm[8]*X + Lm[9]*Y + Lm[10]*Z + Lm[11];
        float z  = fminf(fmaxf(c2, 1e-5f), 100000.0f);
        float vx = c0/z, vy = c1/z, vz = z;
        const float* Am = iaug + cam*16;
        float d0 = Am[0]*vx + Am[1]*vy + Am[2]*vz + Am[3];
        float d1 = Am[4]*vx + Am[5]*vy + Am[6]*vz + Am[7];
        proj[i*12 + cam*2 + 0] = d0 * ((float)(WF-1)/(float)ORIW);
        proj[i*12 + cam*2 + 1] = d1 * ((float)(HF-1)/(float)ORIH);
    }
}

// ---------------- fuse = [pts | sum_cam bilinear(img)] as bf16, 4 ch/thread ---
__global__ __launch_bounds__(256) void k_fuse(const float* __restrict__ pts,
                                              const float* __restrict__ imgt,
                                              const float* __restrict__ proj,
                                              ushort4* __restrict__ fuse4) {
    const int C4 = FDIM/4;                       // 56 groups of 4 channels
    int tid = blockIdx.x * 256 + threadIdx.x;
    if (tid >= MPTS*C4) return;
    int i  = tid / C4;
    int c4 = tid % C4;
    float4 v;
    if (c4 < PDIM/4) {
        v = reinterpret_cast<const float4*>(pts)[i*(PDIM/4) + c4];
    } else {
        int sg = c4 - PDIM/4;                    // float4 group within 96 img ch
        v = make_float4(0.f, 0.f, 0.f, 0.f);
        #pragma unroll
        for (int cam = 0; cam < NCAM; cam++) {
            float x = proj[i*12 + cam*2 + 0];
            float y = proj[i*12 + cam*2 + 1];
            if (x <= -1.0f || x >= (float)WF || y <= -1.0f || y >= (float)HF) continue;
            float x0f = floorf(x), y0f = floorf(y);
            int x0 = (int)x0f, y0 = (int)y0f;
            float wx1 = x - x0f, wy1 = y - y0f;
            float wx0 = 1.f - wx1, wy0 = 1.f - wy1;
            bool vx0 = (x0   >= 0) && (x0   <= WF-1);
            bool vx1 = (x0+1 >= 0) && (x0+1 <= WF-1);
            bool vy0 = (y0   >= 0) && (y0   <= HF-1);
            bool vy1 = (y0+1 >= 0) && (y0+1 <= HF-1);
            const float4* base = reinterpret_cast<const float4*>(imgt) + (size_t)cam*HF*WF*(CIMG/4) + sg;
            #define ACC4(px_, py_, w_) { \
                float4 t = base[((py_)*WF + (px_))*(CIMG/4)]; \
                v.x += t.x*(w_); v.y += t.y*(w_); v.z += t.z*(w_); v.w += t.w*(w_); }
            if (vx0 && vy0) ACC4(x0,   y0,   wx0*wy0);
            if (vx1 && vy0) ACC4(x0+1, y0,   wx1*wy0);
            if (vx0 && vy1) ACC4(x0,   y0+1, wx0*wy1);
            if (vx1 && vy1) ACC4(x0+1, y0+1, wx1*wy1);
            #undef ACC4
        }
    }
    ushort4 o;
    o.x = f32_to_bf16bits(v.x);
    o.y = f32_to_bf16bits(v.y);
    o.z = f32_to_bf16bits(v.z);
    o.w = f32_to_bf16bits(v.w);
    fuse4[tid] = o;
}

// ---------------- pair lists, ballot-aggregated (no per-lane global atomics) --
__global__ __launch_bounds__(256) void k_pairs(const int* __restrict__ vc,
                                               const int* __restrict__ grid,
                                               int* __restrict__ cnt,
                                               int2* __restrict__ pairs) {
    int i = blockIdx.x * 256 + threadIdx.x;
    bool act = (i < MPTS);
    int cz = 0, cy = 0, cx = 0;
    if (act) { cz = vc[i*4+1]; cy = vc[i*4+2]; cx = vc[i*4+3]; }
    __shared__ int s_wcnt[4][27];
    __shared__ int s_wbase[4][27];
    int wv = threadIdx.x >> 6, ln = threadIdx.x & 63;
    int nid[27];
    int rnk[27];
    #pragma unroll
    for (int k = 0; k < 27; k++) {
        if (k == 13) continue;
        int dz = k/9 - 1, dy = (k/3)%3 - 1, dx = k%3 - 1;
        int nz = cz+dz, ny = cy+dy, nx = cx+dx;
        int id = -1;
        if (act && nz >= 0 && nz < GZD && ny >= 0 && ny < GYD && nx >= 0 && nx < GXD)
            id = grid[(nz*GYD + ny)*GXD + nx];
        nid[k] = id;
        unsigned long long m = __ballot(id >= 0);
        if (ln == 0) s_wcnt[wv][k] = __popcll(m);
        rnk[k] = __popcll(m & ((1ull << ln) - 1ull));
    }
    __syncthreads();
    if (threadIdx.x < 27 && threadIdx.x != 13) {
        int k = threadIdx.x;
        int c0 = s_wcnt[0][k], c1 = s_wcnt[1][k], c2 = s_wcnt[2][k], c3 = s_wcnt[3][k];
        int tot = c0 + c1 + c2 + c3;
        int b = (tot > 0) ? atomicAdd(&cnt[k], tot) : 0;
        s_wbase[0][k] = b;
        s_wbase[1][k] = b + c0;
        s_wbase[2][k] = b + c0 + c1;
        s_wbase[3][k] = b + c0 + c1 + c2;
    }
    __syncthreads();
    #pragma unroll
    for (int k = 0; k < 27; k++) {
        if (k == 13) continue;
        if (nid[k] >= 0) {
            int slot = s_wbase[wv][k] + rnk[k];
            if (slot < PAIR_CAP) pairs[k*PAIR_CAP + slot] = make_int2(i, nid[k]);
        }
    }
}

// ---- shared micro-kernel: 32 rows x 224 K x 128 cols, thread = (col, col+64) x 8 rows
__device__ __forceinline__ void gemm_tile(const float (*s_f)[FDIM],
                                          const float* __restrict__ Wk,
                                          int col, int pg,
                                          float* acc0, float* acc1) {
    for (int c0 = 0; c0 < FDIM; c0 += 8) {
        float w0[8], w1[8];
        #pragma unroll
        for (int cc = 0; cc < 8; cc++) {
            w0[cc] = Wk[(c0+cc)*PDIM + col];
            w1[cc] = Wk[(c0+cc)*PDIM + col + 64];
        }
        #pragma unroll
        for (int p = 0; p < 8; p++) {
            const float4* f4 = reinterpret_cast<const float4*>(&s_f[pg*8+p][c0]);
            float4 fa = f4[0], fb = f4[1];
            acc0[p] += fa.x*w0[0]+fa.y*w0[1]+fa.z*w0[2]+fa.w*w0[3]
                     + fb.x*w0[4]+fb.y*w0[5]+fb.z*w0[6]+fb.w*w0[7];
            acc1[p] += fa.x*w1[0]+fa.y*w1[1]+fa.z*w1[2]+fa.w*w1[3]
                     + fb.x*w1[4]+fb.y*w1[5]+fb.z*w1[6]+fb.w*w1[7];
        }
    }
}

__device__ __forceinline__ void fill_tile(float (*s_f)[FDIM], const int* s_j,
                                          const ushort4* __restrict__ fuse4, int tid) {
    for (int idx = tid; idx < 32*(FDIM/4); idx += 256) {
        int r = idx / (FDIM/4), c4 = idx % (FDIM/4);
        int j = s_j[r];
        float4 vv = make_float4(0.f, 0.f, 0.f, 0.f);
        if (j >= 0) {
            ushort4 u = fuse4[j*(FDIM/4) + c4];
            vv.x = bf16bits_to_f32(u.x);
            vv.y = bf16bits_to_f32(u.y);
            vv.z = bf16bits_to_f32(u.z);
            vv.w = bf16bits_to_f32(u.w);
        }
        *reinterpret_cast<float4*>(&s_f[r][c4*4]) = vv;
    }
}

// ---------------- neighbor GEMMs: per (k, 32-pair tile), atomic scatter-add ----
__global__ __launch_bounds__(256) void k_nbr(const int2* __restrict__ pairs,
                                             const int* __restrict__ cnt,
                                             const ushort4* __restrict__ fuse4,
                                             const float* __restrict__ W,
                                             float* __restrict__ out) {
    int k = blockIdx.y;
    if (k >= 13) k += 1;
    int n = cnt[k];
    if (n > PAIR_CAP) n = PAIR_CAP;
    int p0 = blockIdx.x * 32;
    if (p0 >= n) return;
    int nn = min(32, n - p0);

    __shared__ int s_i[32];
    __shared__ int s_j[32];
    __shared__ float s_f[32][FDIM];
    int tid = threadIdx.x;
    if (tid < 32) {
        if (tid < nn) { int2 pr = pairs[k*PAIR_CAP + p0 + tid]; s_i[tid] = pr.x; s_j[tid] = pr.y; }
        else          { s_i[tid] = -1; s_j[tid] = -1; }
    }
    __syncthreads();
    fill_tile(s_f, s_j, fuse4, tid);
    __syncthreads();

    int col = tid & 63;
    int pg  = tid >> 6;
    const float* Wk = W + k*FDIM*PDIM;
    float acc0[8], acc1[8];
    #pragma unroll
    for (int p = 0; p < 8; p++) { acc0[p] = 0.f; acc1[p] = 0.f; }
    gemm_tile(s_f, Wk, col, pg, acc0, acc1);

    #pragma unroll
    for (int p = 0; p < 8; p++) {
        int pr = pg*8 + p;
        int ii = s_i[pr];
        if (ii >= 0) {
            unsafeAtomicAdd(&out[ii*PDIM + col],      acc0[p]);
            unsafeAtomicAdd(&out[ii*PDIM + col + 64], acc1[p]);
        }
    }
}

// ---------------- center GEMM (k=13, all points) + BN + ReLU epilogue ---------
__global__ __launch_bounds__(256) void k_center(const int* __restrict__ vc,
                                                const int* __restrict__ grid,
                                                const ushort4* __restrict__ fuse4,
                                                const float* __restrict__ W,
                                                const float* __restrict__ gamma,
                                                const float* __restrict__ beta,
                                                const float* __restrict__ mean,
                                                const float* __restrict__ var,
                                                float* __restrict__ out) {
    int i0 = blockIdx.x * 32;
    __shared__ int s_j[32];
    __shared__ float s_f[32][FDIM];
    int tid = threadIdx.x;
    if (tid < 32) {
        int i = i0 + tid;
        int nid = -1;
        if (i < MPTS) {
            int cz = vc[i*4+1], cy = vc[i*4+2], cx = vc[i*4+3];
            nid = grid[(cz*GYD + cy)*GXD + cx];
        }
        s_j[tid] = nid;
    }
    __syncthreads();
    fill_tile(s_f, s_j, fuse4, tid);
    __syncthreads();

    int col = tid & 63;
    int pg  = tid >> 6;
    const float* Wk = W + 13*FDIM*PDIM;
    float acc0[8], acc1[8];
    #pragma unroll
    for (int p = 0; p < 8; p++) { acc0[p] = 0.f; acc1[p] = 0.f; }
    gemm_tile(s_f, Wk, col, pg, acc0, acc1);

    float g0 = gamma[col],    b0 = beta[col],    m0 = mean[col],    r0 = rsqrtf(var[col]+BN_EPS);
    float g1 = gamma[col+64], b1 = beta[col+64], m1 = mean[col+64], r1 = rsqrtf(var[col+64]+BN_EPS);
    #pragma unroll
    for (int p = 0; p < 8; p++) {
        int i = i0 + pg*8 + p;
        if (i < MPTS) {
            int o = i*PDIM + col;
            float v0 = out[o] + acc0[p];
            v0 = (v0 - m0)*r0*g0 + b0;
            out[o] = fmaxf(v0, 0.f);
            float v1 = out[o+64] + acc1[p];
            v1 = (v1 - m1)*r1*g1 + b1;
            out[o+64] = fmaxf(v1, 0.f);
        }
    }
}

extern "C" void kernel_launch(void* const* d_in, const int* in_sizes, int n_in,
                              void* d_out, int out_size, void* d_ws, size_t ws_size,
                              hipStream_t stream) {
    const float* pts   = (const float*)d_in[0];
    const int*   vc    = (const int*)d_in[1];
    const float* img   = (const float*)d_in[2];
    const float* l2i   = (const float*)d_in[3];
    const float* iaug  = (const float*)d_in[4];
    const float* laug  = (const float*)d_in[5];
    const float* conv  = (const float*)d_in[6];
    const float* gamma = (const float*)d_in[7];
    const float* beta  = (const float*)d_in[8];
    const float* mean  = (const float*)d_in[9];
    const float* var   = (const float*)d_in[10];
    float* out = (float*)d_out;

    char* ws = (char*)d_ws;
    int*     grid  = (int*)(ws + OFF_GRID);
    float*   imgt  = (float*)(ws + OFF_IMGT);
    float*   proj  = (float*)(ws + OFF_PROJ);
    ushort4* fuse4 = (ushort4*)(ws + OFF_FUSE);
    int*     cnt   = (int*)(ws + OFF_CNT);
    int2*    pairs = (int2*)(ws + OFF_PAIRS);

    hipMemsetAsync(grid, 0xFF, (size_t)NCELLS*4, stream);
    hipMemsetAsync(cnt, 0, 32*4, stream);
    hipMemsetAsync(d_out, 0, (size_t)out_size*4, stream);

    int blocksM = (MPTS + 255)/256;
    k_scatter<<<blocksM, 256, 0, stream>>>(vc, grid);
    k_transpose<<<(NCAM*CIMG*HF*WF + 255)/256, 256, 0, stream>>>(img, imgt);
    k_proj<<<blocksM, 256, 0, stream>>>(vc, l2i, iaug, laug, proj);
    k_fuse<<<(MPTS*(FDIM/4) + 255)/256, 256, 0, stream>>>(pts, imgt, proj, fuse4);
    k_pairs<<<blocksM, 256, 0, stream>>>(vc, grid, cnt, pairs);
    k_nbr<<<dim3(PAIR_CAP/32, 26), 256, 0, stream>>>(pairs, cnt, fuse4, conv, out);
    k_center<<<(MPTS + 31)/32, 256, 0, stream>>>(vc, grid, fuse4, conv,
                                                 gamma, beta, mean, var, out);
}

// Round 3
// 639.081 us; speedup vs baseline: 3.0115x; 1.4644x over previous
//
#include <hip/hip_runtime.h>
#include <hip/hip_bf16.h>

#define MPTS 200000
#define NCAM 6
#define CIMG 96
#define HF 32
#define WF 88
#define PDIM 128
#define FDIM 224
#define FDIM_P 232            // LDS row pad: dword stride 116 ≡ 20 (mod 32) → conflict-free
#define ORIH 256
#define ORIW 704
#define GZD 32
#define GYD 512
#define GXD 448
#define NCELLS (GZD*GYD*GXD)
#define PAIR_CAP 16384
#define BN_EPS 1e-5f

// ---- workspace layout (bytes), all offsets 16B-aligned ----
#define OFF_GRID   0UL            // int[NCELLS]            29,360,128 B
#define OFF_IMGT   29360128UL     // float[6*32*88*96]       6,488,064 B
#define OFF_PROJ   35848192UL     // float[M*12]             9,600,000 B  (reused for WPACK after k_fuse)
#define OFF_WPACK  OFF_PROJ       // bf16[27*7*8*64*8]       1,548,288 B  (overlays proj; stream-ordered)
#define OFF_FUSE   45448192UL     // bf16[M*224]            89,600,000 B
#define OFF_CNT    135048192UL    // int[32]
#define OFF_PAIRS  135048320UL    // int2[27*PAIR_CAP]       3,538,944 B

typedef __attribute__((ext_vector_type(8))) short bf16x8;
typedef __attribute__((ext_vector_type(4))) float f32x4;

__device__ __forceinline__ float bf16bits_to_f32(unsigned short u) {
    return __uint_as_float(((unsigned int)u) << 16);
}
__device__ __forceinline__ unsigned short f32_to_bf16bits(float f) {
    __hip_bfloat16 h = __float2bfloat16(f);   // RNE
    return *reinterpret_cast<unsigned short*>(&h);
}

// ---------------- scatter: grid[cell] = max point index (== last-write-wins) ----
__global__ __launch_bounds__(256) void k_scatter(const int* __restrict__ vc,
                                                 int* __restrict__ grid) {
    int i = blockIdx.x * 256 + threadIdx.x;
    if (i >= MPTS) return;
    int cz = vc[i*4+1], cy = vc[i*4+2], cx = vc[i*4+3];
    atomicMax(&grid[(cz*GYD + cy)*GXD + cx], i);
}

// ---------------- transpose img (cam,C,H,W) -> (cam,H,W,C) for coalesced gathers
__global__ __launch_bounds__(256) void k_transpose(const float* __restrict__ img,
                                                   float* __restrict__ imgt) {
    int tid = blockIdx.x * 256 + threadIdx.x;
    if (tid >= NCAM*CIMG*HF*WF) return;
    int c = tid % CIMG;
    int r = tid / CIMG;
    int x = r % WF;
    int r2 = r / WF;
    int y = r2 % HF;
    int cam = r2 / HF;
    imgt[tid] = img[((cam*CIMG + c)*HF + y)*WF + x];
}

// ---------------- per (point,cam) projection -> feature-map pixel coords ------
__global__ __launch_bounds__(256) void k_proj(const int* __restrict__ vc,
                                              const float* __restrict__ l2i,
                                              const float* __restrict__ iaug,
                                              const float* __restrict__ laug,
                                              float* __restrict__ proj) {
    int i = blockIdx.x * 256 + threadIdx.x;
    if (i >= MPTS) return;
    float cxf = (float)vc[i*4+3], cyf = (float)vc[i*4+2], czf = (float)vc[i*4+1];
    float a00=laug[0],a01=laug[1],a02=laug[2];
    float a10=laug[4],a11=laug[5],a12=laug[6];
    float a20=laug[8],a21=laug[9],a22=laug[10];
    float t0=laug[3], t1=laug[7], t2=laug[11];
    float det = a00*(a11*a22-a12*a21) - a01*(a10*a22-a12*a20) + a02*(a10*a21-a11*a20);
    float id = 1.0f/det;
    float b00 =  (a11*a22-a12*a21)*id, b01 = -(a01*a22-a02*a21)*id, b02 =  (a01*a12-a02*a11)*id;
    float b10 = -(a10*a22-a12*a20)*id, b11 =  (a00*a22-a02*a20)*id, b12 = -(a00*a12-a02*a10)*id;
    float b20 =  (a10*a21-a11*a20)*id, b21 = -(a00*a21-a01*a20)*id, b22 =  (a00*a11-a01*a10)*id;
    float px = cxf-t0, py = cyf-t1, pz = czf-t2;
    float X = b00*px + b01*py + b02*pz;
    float Y = b10*px + b11*py + b12*pz;
    float Z = b20*px + b21*py + b22*pz;
    #pragma unroll
    for (int cam = 0; cam < NCAM; cam++) {
        const float* Lm = l2i + cam*16;
        float c0 = Lm[0]*X + Lm[1]*Y + Lm[2]*Z  + Lm[3];
        float c1 = Lm[4]*X + Lm[5]*Y + Lm[6]*Z  + Lm[7];
        float c2 = Lm[8]*X + Lm[9]*Y + Lm[10]*Z + Lm[11];
        float z  = fminf(fmaxf(c2, 1e-5f), 100000.0f);
        float vx = c0/z, vy = c1/z, vz = z;
        const float* Am = iaug + cam*16;
        float d0 = Am[0]*vx + Am[1]*vy + Am[2]*vz + Am[3];
        float d1 = Am[4]*vx + Am[5]*vy + Am[6]*vz + Am[7];
        proj[i*12 + cam*2 + 0] = d0 * ((float)(WF-1)/(float)ORIW);
        proj[i*12 + cam*2 + 1] = d1 * ((float)(HF-1)/(float)ORIH);
    }
}

// ---------------- fuse = [pts | sum_cam bilinear(img)] as bf16, 4 ch/thread ---
__global__ __launch_bounds__(256) void k_fuse(const float* __restrict__ pts,
                                              const float* __restrict__ imgt,
                                              const float* __restrict__ proj,
                                              ushort4* __restrict__ fuse4) {
    const int C4 = FDIM/4;                       // 56 groups of 4 channels
    int tid = blockIdx.x * 256 + threadIdx.x;
    if (tid >= MPTS*C4) return;
    int i  = tid / C4;
    int c4 = tid % C4;
    float4 v;
    if (c4 < PDIM/4) {
        v = reinterpret_cast<const float4*>(pts)[i*(PDIM/4) + c4];
    } else {
        int sg = c4 - PDIM/4;                    // float4 group within 96 img ch
        v = make_float4(0.f, 0.f, 0.f, 0.f);
        #pragma unroll
        for (int cam = 0; cam < NCAM; cam++) {
            float x = proj[i*12 + cam*2 + 0];
            float y = proj[i*12 + cam*2 + 1];
            if (x <= -1.0f || x >= (float)WF || y <= -1.0f || y >= (float)HF) continue;
            float x0f = floorf(x), y0f = floorf(y);
            int x0 = (int)x0f, y0 = (int)y0f;
            float wx1 = x - x0f, wy1 = y - y0f;
            float wx0 = 1.f - wx1, wy0 = 1.f - wy1;
            bool vx0 = (x0   >= 0) && (x0   <= WF-1);
            bool vx1 = (x0+1 >= 0) && (x0+1 <= WF-1);
            bool vy0 = (y0   >= 0) && (y0   <= HF-1);
            bool vy1 = (y0+1 >= 0) && (y0+1 <= HF-1);
            const float4* base = reinterpret_cast<const float4*>(imgt) + (size_t)cam*HF*WF*(CIMG/4) + sg;
            #define ACC4(px_, py_, w_) { \
                float4 t = base[((py_)*WF + (px_))*(CIMG/4)]; \
                v.x += t.x*(w_); v.y += t.y*(w_); v.z += t.z*(w_); v.w += t.w*(w_); }
            if (vx0 && vy0) ACC4(x0,   y0,   wx0*wy0);
            if (vx1 && vy0) ACC4(x0+1, y0,   wx1*wy0);
            if (vx0 && vy1) ACC4(x0,   y0+1, wx0*wy1);
            if (vx1 && vy1) ACC4(x0+1, y0+1, wx1*wy1);
            #undef ACC4
        }
    }
    ushort4 o;
    o.x = f32_to_bf16bits(v.x);
    o.y = f32_to_bf16bits(v.y);
    o.z = f32_to_bf16bits(v.z);
    o.w = f32_to_bf16bits(v.w);
    fuse4[tid] = o;
}

// ---------------- pack conv_w into bf16 MFMA B-fragment layout ----------------
// wp element (k27, kk, nt, lane, j) = W[k27][kk*32 + (lane>>4)*8 + j][nt*16 + (lane&15)]
// so each lane's 8 k-values are 16B contiguous; lanes coalesce.
__global__ __launch_bounds__(256) void k_wpack(const float* __restrict__ conv,
                                               ushort4* __restrict__ wp) {
    int tid = blockIdx.x * 256 + threadIdx.x;
    if (tid >= 27*7*8*64) return;
    int lane = tid & 63;
    int nt   = (tid >> 6) & 7;
    int kk   = (tid >> 9) % 7;
    int k27  = tid / 3584;
    int n     = nt*16 + (lane & 15);
    int kbase = kk*32 + (lane >> 4)*8;
    const float* src = conv + ((size_t)k27*FDIM + kbase)*PDIM + n;
    ushort4 lo, hi;
    lo.x = f32_to_bf16bits(src[0*PDIM]);
    lo.y = f32_to_bf16bits(src[1*PDIM]);
    lo.z = f32_to_bf16bits(src[2*PDIM]);
    lo.w = f32_to_bf16bits(src[3*PDIM]);
    hi.x = f32_to_bf16bits(src[4*PDIM]);
    hi.y = f32_to_bf16bits(src[5*PDIM]);
    hi.z = f32_to_bf16bits(src[6*PDIM]);
    hi.w = f32_to_bf16bits(src[7*PDIM]);
    wp[tid*2]   = lo;
    wp[tid*2+1] = hi;
}

// ---------------- pair lists, ballot-aggregated -------------------------------
__global__ __launch_bounds__(256) void k_pairs(const int* __restrict__ vc,
                                               const int* __restrict__ grid,
                                               int* __restrict__ cnt,
                                               int2* __restrict__ pairs) {
    int i = blockIdx.x * 256 + threadIdx.x;
    bool act = (i < MPTS);
    int cz = 0, cy = 0, cx = 0;
    if (act) { cz = vc[i*4+1]; cy = vc[i*4+2]; cx = vc[i*4+3]; }
    __shared__ int s_wcnt[4][27];
    __shared__ int s_wbase[4][27];
    int wv = threadIdx.x >> 6, ln = threadIdx.x & 63;
    int nid[27];
    int rnk[27];
    #pragma unroll
    for (int k = 0; k < 27; k++) {
        if (k == 13) continue;
        int dz = k/9 - 1, dy = (k/3)%3 - 1, dx = k%3 - 1;
        int nz = cz+dz, ny = cy+dy, nx = cx+dx;
        int id = -1;
        if (act && nz >= 0 && nz < GZD && ny >= 0 && ny < GYD && nx >= 0 && nx < GXD)
            id = grid[(nz*GYD + ny)*GXD + nx];
        nid[k] = id;
        unsigned long long m = __ballot(id >= 0);
        if (ln == 0) s_wcnt[wv][k] = __popcll(m);
        rnk[k] = __popcll(m & ((1ull << ln) - 1ull));
    }
    __syncthreads();
    if (threadIdx.x < 27 && threadIdx.x != 13) {
        int k = threadIdx.x;
        int c0 = s_wcnt[0][k], c1 = s_wcnt[1][k], c2 = s_wcnt[2][k], c3 = s_wcnt[3][k];
        int tot = c0 + c1 + c2 + c3;
        int b = (tot > 0) ? atomicAdd(&cnt[k], tot) : 0;
        s_wbase[0][k] = b;
        s_wbase[1][k] = b + c0;
        s_wbase[2][k] = b + c0 + c1;
        s_wbase[3][k] = b + c0 + c1 + c2;
    }
    __syncthreads();
    #pragma unroll
    for (int k = 0; k < 27; k++) {
        if (k == 13) continue;
        if (nid[k] >= 0) {
            int slot = s_wbase[wv][k] + rnk[k];
            if (slot < PAIR_CAP) pairs[k*PAIR_CAP + slot] = make_int2(i, nid[k]);
        }
    }
}

// ---- MFMA micro-kernel pieces ------------------------------------------------
// LDS tile: 32 rows of fuse (bf16), padded row FDIM_P=232 shorts.
__device__ __forceinline__ void fill_tile_bf16(unsigned short (*s_fb)[FDIM_P],
                                               const int* s_j,
                                               const uint4* __restrict__ fuse16,
                                               int tid) {
    for (int idx = tid; idx < 32*28; idx += 256) {   // 28 x 16B chunks per row
        int r = idx / 28, c = idx % 28;
        int j = s_j[r];
        uint4 v = make_uint4(0u, 0u, 0u, 0u);
        if (j >= 0) v = fuse16[(size_t)j*28 + c];
        *reinterpret_cast<uint4*>(&s_fb[r][c*8]) = v;
    }
}

// 32x128 tile GEMM: wave wv owns cols [wv*32, wv*32+32), 2x2 MFMA tiles.
__device__ __forceinline__ void gemm_mfma(const unsigned short (*s_fb)[FDIM_P],
                                          const bf16x8* __restrict__ wpb,
                                          int k27, int lane, int wv,
                                          f32x4 acc[2][2]) {
    int quad = lane >> 4, l15 = lane & 15;
    #pragma unroll
    for (int kk = 0; kk < 7; kk++) {
        bf16x8 a0 = *reinterpret_cast<const bf16x8*>(&s_fb[l15     ][kk*32 + quad*8]);
        bf16x8 a1 = *reinterpret_cast<const bf16x8*>(&s_fb[16 + l15][kk*32 + quad*8]);
        bf16x8 b0 = wpb[(((k27*7 + kk)*8) + wv*2 + 0)*64 + lane];
        bf16x8 b1 = wpb[(((k27*7 + kk)*8) + wv*2 + 1)*64 + lane];
        acc[0][0] = __builtin_amdgcn_mfma_f32_16x16x32_bf16(a0, b0, acc[0][0], 0, 0, 0);
        acc[1][0] = __builtin_amdgcn_mfma_f32_16x16x32_bf16(a1, b0, acc[1][0], 0, 0, 0);
        acc[0][1] = __builtin_amdgcn_mfma_f32_16x16x32_bf16(a0, b1, acc[0][1], 0, 0, 0);
        acc[1][1] = __builtin_amdgcn_mfma_f32_16x16x32_bf16(a1, b1, acc[1][1], 0, 0, 0);
    }
}

// ---------------- neighbor GEMMs: per (k, 32-pair tile), atomic scatter-add ----
__global__ __launch_bounds__(256) void k_nbr(const int2* __restrict__ pairs,
                                             const int* __restrict__ cnt,
                                             const uint4* __restrict__ fuse16,
                                             const bf16x8* __restrict__ wpb,
                                             float* __restrict__ out) {
    int k = blockIdx.y;
    if (k >= 13) k += 1;
    int n = cnt[k];
    if (n > PAIR_CAP) n = PAIR_CAP;
    int p0 = blockIdx.x * 32;
    if (p0 >= n) return;
    int nn = min(32, n - p0);

    __shared__ int s_i[32];
    __shared__ int s_j[32];
    __shared__ unsigned short s_fb[32][FDIM_P];
    int tid = threadIdx.x;
    if (tid < 32) {
        if (tid < nn) { int2 pr = pairs[k*PAIR_CAP + p0 + tid]; s_i[tid] = pr.x; s_j[tid] = pr.y; }
        else          { s_i[tid] = -1; s_j[tid] = -1; }
    }
    __syncthreads();
    fill_tile_bf16(s_fb, s_j, fuse16, tid);
    __syncthreads();

    int lane = tid & 63, wv = tid >> 6;
    int quad = lane >> 4, l15 = lane & 15;
    f32x4 acc[2][2] = {};
    gemm_mfma(s_fb, wpb, k, lane, wv, acc);

    #pragma unroll
    for (int nt = 0; nt < 2; nt++) {
        int col = wv*32 + nt*16 + l15;
        #pragma unroll
        for (int mt = 0; mt < 2; mt++) {
            #pragma unroll
            for (int r = 0; r < 4; r++) {
                int row = mt*16 + quad*4 + r;
                int ii = s_i[row];
                if (ii >= 0) unsafeAtomicAdd(&out[(size_t)ii*PDIM + col], acc[mt][nt][r]);
            }
        }
    }
}

// ---------------- center GEMM (k=13, all points) + BN + ReLU epilogue ---------
__global__ __launch_bounds__(256) void k_center(const int* __restrict__ vc,
                                                const int* __restrict__ grid,
                                                const uint4* __restrict__ fuse16,
                                                const bf16x8* __restrict__ wpb,
                                                const float* __restrict__ gamma,
                                                const float* __restrict__ beta,
                                                const float* __restrict__ mean,
                                                const float* __restrict__ var,
                                                float* __restrict__ out) {
    int i0 = blockIdx.x * 32;                      // 200000 % 32 == 0, no tail
    __shared__ int s_j[32];
    __shared__ unsigned short s_fb[32][FDIM_P];
    int tid = threadIdx.x;
    if (tid < 32) {
        int i = i0 + tid;
        int cz = vc[i*4+1], cy = vc[i*4+2], cx = vc[i*4+3];
        s_j[tid] = grid[(cz*GYD + cy)*GXD + cx];   // always >= 0 (cell occupied by i)
    }
    __syncthreads();
    fill_tile_bf16(s_fb, s_j, fuse16, tid);
    __syncthreads();

    int lane = tid & 63, wv = tid >> 6;
    int quad = lane >> 4, l15 = lane & 15;
    f32x4 acc[2][2] = {};
    gemm_mfma(s_fb, wpb, 13, lane, wv, acc);

    #pragma unroll
    for (int nt = 0; nt < 2; nt++) {
        int col = wv*32 + nt*16 + l15;
        float g  = gamma[col], bb = beta[col], mn = mean[col];
        float rs = rsqrtf(var[col] + BN_EPS);
        #pragma unroll
        for (int mt = 0; mt < 2; mt++) {
            #pragma unroll
            for (int r = 0; r < 4; r++) {
                int row = mt*16 + quad*4 + r;
                size_t o = (size_t)(i0 + row)*PDIM + col;
                float v = out[o] + acc[mt][nt][r];   // neighbor atomics already landed
                v = (v - mn)*rs*g + bb;
                out[o] = fmaxf(v, 0.f);
            }
        }
    }
}

extern "C" void kernel_launch(void* const* d_in, const int* in_sizes, int n_in,
                              void* d_out, int out_size, void* d_ws, size_t ws_size,
                              hipStream_t stream) {
    const float* pts   = (const float*)d_in[0];
    const int*   vc    = (const int*)d_in[1];
    const float* img   = (const float*)d_in[2];
    const float* l2i   = (const float*)d_in[3];
    const float* iaug  = (const float*)d_in[4];
    const float* laug  = (const float*)d_in[5];
    const float* conv  = (const float*)d_in[6];
    const float* gamma = (const float*)d_in[7];
    const float* beta  = (const float*)d_in[8];
    const float* mean  = (const float*)d_in[9];
    const float* var   = (const float*)d_in[10];
    float* out = (float*)d_out;

    char* ws = (char*)d_ws;
    int*     grid  = (int*)(ws + OFF_GRID);
    float*   imgt  = (float*)(ws + OFF_IMGT);
    float*   proj  = (float*)(ws + OFF_PROJ);
    ushort4* wp    = (ushort4*)(ws + OFF_WPACK);   // overlays proj (used after k_fuse)
    ushort4* fuse4 = (ushort4*)(ws + OFF_FUSE);
    int*     cnt   = (int*)(ws + OFF_CNT);
    int2*    pairs = (int2*)(ws + OFF_PAIRS);
    const uint4*  fuse16 = (const uint4*)fuse4;
    const bf16x8* wpb    = (const bf16x8*)wp;

    hipMemsetAsync(grid, 0xFF, (size_t)NCELLS*4, stream);
    hipMemsetAsync(cnt, 0, 32*4, stream);
    hipMemsetAsync(d_out, 0, (size_t)out_size*4, stream);

    int blocksM = (MPTS + 255)/256;
    k_scatter<<<blocksM, 256, 0, stream>>>(vc, grid);
    k_transpose<<<(NCAM*CIMG*HF*WF + 255)/256, 256, 0, stream>>>(img, imgt);
    k_proj<<<blocksM, 256, 0, stream>>>(vc, l2i, iaug, laug, proj);
    k_fuse<<<(MPTS*(FDIM/4) + 255)/256, 256, 0, stream>>>(pts, imgt, proj, fuse4);
    k_wpack<<<(27*7*8*64 + 255)/256, 256, 0, stream>>>(conv, wp);   // after k_fuse (proj overlay)
    k_pairs<<<blocksM, 256, 0, stream>>>(vc, grid, cnt, pairs);
    k_nbr<<<dim3(PAIR_CAP/32, 26), 256, 0, stream>>>(pairs, cnt, fuse16, wpb, out);
    k_center<<<(MPTS + 31)/32, 256, 0, stream>>>(vc, grid, fuse16, wpb,
                                                 gamma, beta, mean, var, out);
}

// Round 4
// 508.541 us; speedup vs baseline: 3.7846x; 1.2567x over previous
//
#include <hip/hip_runtime.h>
#include <hip/hip_bf16.h>
#include <hip/hip_fp16.h>

#define MPTS 200000
#define NCAM 6
#define CIMG 96
#define HF 32
#define WF 88
#define PDIM 128
#define FDIM 224
#define FDIM_P 232            // LDS row pad: dword stride 116 ≡ 20 (mod 32) → conflict-free
#define ORIH 256
#define ORIW 704
#define GZD 32
#define GYD 512
#define GXD 448
#define NCELLS (GZD*GYD*GXD)
#define PAIR_CAP 16384
#define BN_EPS 1e-5f

// ---- workspace layout (bytes), all offsets 16B-aligned ----
#define OFF_GRID   0UL            // int[NCELLS]            29,360,128 B
#define OFF_IMGT   29360128UL     // float[6*32*88*96]       6,488,064 B
#define OFF_DESCM  35848192UL     // uint[M*6]               4,800,000 B  (sample meta)
#define OFF_WPACK  OFF_DESCM      //                         1,548,288 B  (overlays desc_meta AFTER k_fuse)
#define OFF_DESCW  40648192UL     // uint2[M*6]              9,600,000 B  (f16 corner weights)
#define OFF_FUSE   50248192UL     // bf16[M*224]            89,600,000 B
#define OFF_CNT    139848192UL    // int[32]
#define OFF_PAIRS  139848320UL    // int2[27*PAIR_CAP]       3,538,944 B
// total 143,387,264 B

#define BPTS (MPTS*32/256)        // 25000 blocks: pts copy (M*32 float4 threads)
#define BIMG (MPTS*24/256)        // 18750 blocks: img sample (M*24 threads)

typedef __attribute__((ext_vector_type(8))) short bf16x8;
typedef __attribute__((ext_vector_type(4))) float f32x4;

__device__ __forceinline__ unsigned short f32_to_bf16bits(float f) {
    __hip_bfloat16 h = __float2bfloat16(f);   // RNE
    return *reinterpret_cast<unsigned short*>(&h);
}

// ---------------- scatter: grid[cell] = max point index (== last-write-wins) ----
__global__ __launch_bounds__(256) void k_scatter(const int* __restrict__ vc,
                                                 int* __restrict__ grid) {
    int i = blockIdx.x * 256 + threadIdx.x;
    if (i >= MPTS) return;
    int cz = vc[i*4+1], cy = vc[i*4+2], cx = vc[i*4+3];
    atomicMax(&grid[(cz*GYD + cy)*GXD + cx], i);
}

// ---------------- transpose img (cam,C,H,W) -> (cam,H,W,C) for coalesced gathers
__global__ __launch_bounds__(256) void k_transpose(const float* __restrict__ img,
                                                   float* __restrict__ imgt) {
    int tid = blockIdx.x * 256 + threadIdx.x;
    if (tid >= NCAM*CIMG*HF*WF) return;
    int c = tid % CIMG;
    int r = tid / CIMG;
    int x = r % WF;
    int r2 = r / WF;
    int y = r2 % HF;
    int cam = r2 / HF;
    imgt[tid] = img[((cam*CIMG + c)*HF + y)*WF + x];
}

// ------- projection + full bilinear setup -> per-(point,cam) descriptor ------
// meta: bit15 = active, bits0..12 = clamped base pixel (yb*WF+xb), xb<=WF-2, yb<=HF-2
// wts:  4 corner weights (validity folded in: invalid corner -> weight 0) as f16x4
__global__ __launch_bounds__(256) void k_proj(const int* __restrict__ vc,
                                              const float* __restrict__ l2i,
                                              const float* __restrict__ iaug,
                                              const float* __restrict__ laug,
                                              unsigned int* __restrict__ meta,
                                              uint2* __restrict__ wts) {
    int i = blockIdx.x * 256 + threadIdx.x;
    if (i >= MPTS) return;
    float cxf = (float)vc[i*4+3], cyf = (float)vc[i*4+2], czf = (float)vc[i*4+1];
    float a00=laug[0],a01=laug[1],a02=laug[2];
    float a10=laug[4],a11=laug[5],a12=laug[6];
    float a20=laug[8],a21=laug[9],a22=laug[10];
    float t0=laug[3], t1=laug[7], t2=laug[11];
    float det = a00*(a11*a22-a12*a21) - a01*(a10*a22-a12*a20) + a02*(a10*a21-a11*a20);
    float id = 1.0f/det;
    float b00 =  (a11*a22-a12*a21)*id, b01 = -(a01*a22-a02*a21)*id, b02 =  (a01*a12-a02*a11)*id;
    float b10 = -(a10*a22-a12*a20)*id, b11 =  (a00*a22-a02*a20)*id, b12 = -(a00*a12-a02*a10)*id;
    float b20 =  (a10*a21-a11*a20)*id, b21 = -(a00*a21-a01*a20)*id, b22 =  (a00*a11-a01*a10)*id;
    float px = cxf-t0, py = cyf-t1, pz = czf-t2;
    float X = b00*px + b01*py + b02*pz;
    float Y = b10*px + b11*py + b12*pz;
    float Z = b20*px + b21*py + b22*pz;
    #pragma unroll
    for (int cam = 0; cam < NCAM; cam++) {
        const float* Lm = l2i + cam*16;
        float c0 = Lm[0]*X + Lm[1]*Y + Lm[2]*Z  + Lm[3];
        float c1 = Lm[4]*X + Lm[5]*Y + Lm[6]*Z  + Lm[7];
        float c2 = Lm[8]*X + Lm[9]*Y + Lm[10]*Z + Lm[11];
        float z  = fminf(fmaxf(c2, 1e-5f), 100000.0f);
        float vx = c0/z, vy = c1/z, vz = z;
        const float* Am = iaug + cam*16;
        float d0 = Am[0]*vx + Am[1]*vy + Am[2]*vz + Am[3];
        float d1 = Am[4]*vx + Am[5]*vy + Am[6]*vz + Am[7];
        float x = d0 * ((float)(WF-1)/(float)ORIW);
        float y = d1 * ((float)(HF-1)/(float)ORIH);
        bool act = (x > -1.0f) && (x < (float)WF) && (y > -1.0f) && (y < (float)HF);
        float x0f = floorf(x), y0f = floorf(y);
        int x0 = (int)x0f, y0 = (int)y0f;
        float wx1 = x - x0f, wy1 = y - y0f;
        float wx0 = 1.f - wx1, wy0 = 1.f - wy1;
        // remap to clamped base so all 4 addresses are in-bounds; zero invalid weights
        float ux0, ux1, uy0, uy1;
        if (x0 < 0)            { ux0 = wx1; ux1 = 0.f; }
        else if (x0 >= WF-1)   { ux0 = 0.f; ux1 = wx0; }   // base=WF-2, true corner at base+1
        else                   { ux0 = wx0; ux1 = wx1; }
        if (y0 < 0)            { uy0 = wy1; uy1 = 0.f; }
        else if (y0 >= HF-1)   { uy0 = 0.f; uy1 = wy0; }
        else                   { uy0 = wy0; uy1 = wy1; }
        int xb = min(max(x0, 0), WF-2);
        int yb = min(max(y0, 0), HF-2);
        unsigned int m = 0u;
        __half2 h01 = __floats2half2_rn(0.f, 0.f), h23 = h01;
        if (act) {
            m = 0x8000u | (unsigned int)(yb*WF + xb);
            h01 = __floats2half2_rn(ux0*uy0, ux1*uy0);
            h23 = __floats2half2_rn(ux0*uy1, ux1*uy1);
        }
        meta[i*6 + cam] = m;
        uint2 wv;
        wv.x = *reinterpret_cast<unsigned int*>(&h01);
        wv.y = *reinterpret_cast<unsigned int*>(&h23);
        wts[i*6 + cam] = wv;
    }
}

// ------- fuse: blocks [0,BPTS) stream pts->bf16; blocks [BPTS,..) sample img --
__global__ __launch_bounds__(256) void k_fuse(const float4* __restrict__ pts4,
                                              const float4* __restrict__ imgt4,
                                              const unsigned int* __restrict__ meta,
                                              const uint2* __restrict__ wts,
                                              ushort4* __restrict__ fuse4) {
    int b = blockIdx.x;
    if (b < BPTS) {
        int t = b*256 + threadIdx.x;             // t = i*32 + c4  (pts is contiguous)
        int i = t >> 5, c4 = t & 31;
        float4 v = pts4[t];
        ushort4 o;
        o.x = f32_to_bf16bits(v.x); o.y = f32_to_bf16bits(v.y);
        o.z = f32_to_bf16bits(v.z); o.w = f32_to_bf16bits(v.w);
        fuse4[i*56 + c4] = o;
    } else {
        int t = (b - BPTS)*256 + threadIdx.x;    // t over M*24
        int i = t / 24, sg = t % 24;
        unsigned int m[NCAM]; uint2 w[NCAM];
        #pragma unroll
        for (int cam = 0; cam < NCAM; cam++) { m[cam] = meta[i*6+cam]; w[cam] = wts[i*6+cam]; }
        float4 acc = make_float4(0.f, 0.f, 0.f, 0.f);
        #pragma unroll
        for (int cam = 0; cam < NCAM; cam++) {
            if (m[cam] & 0x8000u) {
                int pix = (int)(m[cam] & 0x7FFFu & 0x1FFF);
                const float4* base = imgt4 + (size_t)cam*(HF*WF*(CIMG/4)) + (size_t)pix*(CIMG/4) + sg;
                float4 t00 = base[0];
                float4 t01 = base[CIMG/4];
                float4 t10 = base[WF*(CIMG/4)];
                float4 t11 = base[(WF+1)*(CIMG/4)];
                float2 w01 = __half22float2(*reinterpret_cast<const __half2*>(&w[cam].x));
                float2 w23 = __half22float2(*reinterpret_cast<const __half2*>(&w[cam].y));
                acc.x += t00.x*w01.x + t01.x*w01.y + t10.x*w23.x + t11.x*w23.y;
                acc.y += t00.y*w01.x + t01.y*w01.y + t10.y*w23.x + t11.y*w23.y;
                acc.z += t00.z*w01.x + t01.z*w01.y + t10.z*w23.x + t11.z*w23.y;
                acc.w += t00.w*w01.x + t01.w*w01.y + t10.w*w23.x + t11.w*w23.y;
            }
        }
        ushort4 o;
        o.x = f32_to_bf16bits(acc.x); o.y = f32_to_bf16bits(acc.y);
        o.z = f32_to_bf16bits(acc.z); o.w = f32_to_bf16bits(acc.w);
        fuse4[i*56 + 32 + sg] = o;
    }
}

// ---------------- pack conv_w into bf16 MFMA B-fragment layout ----------------
__global__ __launch_bounds__(256) void k_wpack(const float* __restrict__ conv,
                                               ushort4* __restrict__ wp) {
    int tid = blockIdx.x * 256 + threadIdx.x;
    if (tid >= 27*7*8*64) return;
    int lane = tid & 63;
    int nt   = (tid >> 6) & 7;
    int kk   = (tid >> 9) % 7;
    int k27  = tid / 3584;
    int n     = nt*16 + (lane & 15);
    int kbase = kk*32 + (lane >> 4)*8;
    const float* src = conv + ((size_t)k27*FDIM + kbase)*PDIM + n;
    ushort4 lo, hi;
    lo.x = f32_to_bf16bits(src[0*PDIM]);
    lo.y = f32_to_bf16bits(src[1*PDIM]);
    lo.z = f32_to_bf16bits(src[2*PDIM]);
    lo.w = f32_to_bf16bits(src[3*PDIM]);
    hi.x = f32_to_bf16bits(src[4*PDIM]);
    hi.y = f32_to_bf16bits(src[5*PDIM]);
    hi.z = f32_to_bf16bits(src[6*PDIM]);
    hi.w = f32_to_bf16bits(src[7*PDIM]);
    wp[tid*2]   = lo;
    wp[tid*2+1] = hi;
}

// ---------------- pair lists, ballot-aggregated -------------------------------
__global__ __launch_bounds__(256) void k_pairs(const int* __restrict__ vc,
                                               const int* __restrict__ grid,
                                               int* __restrict__ cnt,
                                               int2* __restrict__ pairs) {
    int i = blockIdx.x * 256 + threadIdx.x;
    bool act = (i < MPTS);
    int cz = 0, cy = 0, cx = 0;
    if (act) { cz = vc[i*4+1]; cy = vc[i*4+2]; cx = vc[i*4+3]; }
    __shared__ int s_wcnt[4][27];
    __shared__ int s_wbase[4][27];
    int wv = threadIdx.x >> 6, ln = threadIdx.x & 63;
    int nid[27];
    int rnk[27];
    #pragma unroll
    for (int k = 0; k < 27; k++) {
        if (k == 13) continue;
        int dz = k/9 - 1, dy = (k/3)%3 - 1, dx = k%3 - 1;
        int nz = cz+dz, ny = cy+dy, nx = cx+dx;
        int id = -1;
        if (act && nz >= 0 && nz < GZD && ny >= 0 && ny < GYD && nx >= 0 && nx < GXD)
            id = grid[(nz*GYD + ny)*GXD + nx];
        nid[k] = id;
        unsigned long long mm = __ballot(id >= 0);
        if (ln == 0) s_wcnt[wv][k] = __popcll(mm);
        rnk[k] = __popcll(mm & ((1ull << ln) - 1ull));
    }
    __syncthreads();
    if (threadIdx.x < 27 && threadIdx.x != 13) {
        int k = threadIdx.x;
        int c0 = s_wcnt[0][k], c1 = s_wcnt[1][k], c2 = s_wcnt[2][k], c3 = s_wcnt[3][k];
        int tot = c0 + c1 + c2 + c3;
        int bse = (tot > 0) ? atomicAdd(&cnt[k], tot) : 0;
        s_wbase[0][k] = bse;
        s_wbase[1][k] = bse + c0;
        s_wbase[2][k] = bse + c0 + c1;
        s_wbase[3][k] = bse + c0 + c1 + c2;
    }
    __syncthreads();
    #pragma unroll
    for (int k = 0; k < 27; k++) {
        if (k == 13) continue;
        if (nid[k] >= 0) {
            int slot = s_wbase[wv][k] + rnk[k];
            if (slot < PAIR_CAP) pairs[k*PAIR_CAP + slot] = make_int2(i, nid[k]);
        }
    }
}

// ---- MFMA micro-kernel pieces ------------------------------------------------
__device__ __forceinline__ void fill_tile_bf16(unsigned short (*s_fb)[FDIM_P],
                                               const int* s_j,
                                               const uint4* __restrict__ fuse16,
                                               int tid) {
    for (int idx = tid; idx < 32*28; idx += 256) {
        int r = idx / 28, c = idx % 28;
        int j = s_j[r];
        uint4 v = make_uint4(0u, 0u, 0u, 0u);
        if (j >= 0) v = fuse16[(size_t)j*28 + c];
        *reinterpret_cast<uint4*>(&s_fb[r][c*8]) = v;
    }
}

__device__ __forceinline__ void gemm_mfma(const unsigned short (*s_fb)[FDIM_P],
                                          const bf16x8* __restrict__ wpb,
                                          int k27, int lane, int wv,
                                          f32x4 acc[2][2]) {
    int quad = lane >> 4, l15 = lane & 15;
    #pragma unroll
    for (int kk = 0; kk < 7; kk++) {
        bf16x8 a0 = *reinterpret_cast<const bf16x8*>(&s_fb[l15     ][kk*32 + quad*8]);
        bf16x8 a1 = *reinterpret_cast<const bf16x8*>(&s_fb[16 + l15][kk*32 + quad*8]);
        bf16x8 b0 = wpb[(((k27*7 + kk)*8) + wv*2 + 0)*64 + lane];
        bf16x8 b1 = wpb[(((k27*7 + kk)*8) + wv*2 + 1)*64 + lane];
        acc[0][0] = __builtin_amdgcn_mfma_f32_16x16x32_bf16(a0, b0, acc[0][0], 0, 0, 0);
        acc[1][0] = __builtin_amdgcn_mfma_f32_16x16x32_bf16(a1, b0, acc[1][0], 0, 0, 0);
        acc[0][1] = __builtin_amdgcn_mfma_f32_16x16x32_bf16(a0, b1, acc[0][1], 0, 0, 0);
        acc[1][1] = __builtin_amdgcn_mfma_f32_16x16x32_bf16(a1, b1, acc[1][1], 0, 0, 0);
    }
}

// ---------------- neighbor GEMMs: per (k, 32-pair tile), atomic scatter-add ----
__global__ __launch_bounds__(256) void k_nbr(const int2* __restrict__ pairs,
                                             const int* __restrict__ cnt,
                                             const uint4* __restrict__ fuse16,
                                             const bf16x8* __restrict__ wpb,
                                             float* __restrict__ out) {
    int k = blockIdx.y;
    if (k >= 13) k += 1;
    int n = cnt[k];
    if (n > PAIR_CAP) n = PAIR_CAP;
    int p0 = blockIdx.x * 32;
    if (p0 >= n) return;
    int nn = min(32, n - p0);

    __shared__ int s_i[32];
    __shared__ int s_j[32];
    __shared__ unsigned short s_fb[32][FDIM_P];
    int tid = threadIdx.x;
    if (tid < 32) {
        if (tid < nn) { int2 pr = pairs[k*PAIR_CAP + p0 + tid]; s_i[tid] = pr.x; s_j[tid] = pr.y; }
        else          { s_i[tid] = -1; s_j[tid] = -1; }
    }
    __syncthreads();
    fill_tile_bf16(s_fb, s_j, fuse16, tid);
    __syncthreads();

    int lane = tid & 63, wv = tid >> 6;
    int quad = lane >> 4, l15 = lane & 15;
    f32x4 acc[2][2] = {};
    gemm_mfma(s_fb, wpb, k, lane, wv, acc);

    #pragma unroll
    for (int nt = 0; nt < 2; nt++) {
        int col = wv*32 + nt*16 + l15;
        #pragma unroll
        for (int mt = 0; mt < 2; mt++) {
            #pragma unroll
            for (int r = 0; r < 4; r++) {
                int row = mt*16 + quad*4 + r;
                int ii = s_i[row];
                if (ii >= 0) unsafeAtomicAdd(&out[(size_t)ii*PDIM + col], acc[mt][nt][r]);
            }
        }
    }
}

// ---------------- center GEMM (k=13, all points) + BN + ReLU epilogue ---------
__global__ __launch_bounds__(256) void k_center(const int* __restrict__ vc,
                                                const int* __restrict__ grid,
                                                const uint4* __restrict__ fuse16,
                                                const bf16x8* __restrict__ wpb,
                                                const float* __restrict__ gamma,
                                                const float* __restrict__ beta,
                                                const float* __restrict__ mean,
                                                const float* __restrict__ var,
                                                float* __restrict__ out) {
    int i0 = blockIdx.x * 32;
    __shared__ int s_j[32];
    __shared__ unsigned short s_fb[32][FDIM_P];
    int tid = threadIdx.x;
    if (tid < 32) {
        int i = i0 + tid;
        int cz = vc[i*4+1], cy = vc[i*4+2], cx = vc[i*4+3];
        s_j[tid] = grid[(cz*GYD + cy)*GXD + cx];
    }
    __syncthreads();
    fill_tile_bf16(s_fb, s_j, fuse16, tid);
    __syncthreads();

    int lane = tid & 63, wv = tid >> 6;
    int quad = lane >> 4, l15 = lane & 15;
    f32x4 acc[2][2] = {};
    gemm_mfma(s_fb, wpb, 13, lane, wv, acc);

    #pragma unroll
    for (int nt = 0; nt < 2; nt++) {
        int col = wv*32 + nt*16 + l15;
        float g  = gamma[col], bb = beta[col], mn = mean[col];
        float rs = rsqrtf(var[col] + BN_EPS);
        #pragma unroll
        for (int mt = 0; mt < 2; mt++) {
            #pragma unroll
            for (int r = 0; r < 4; r++) {
                int row = mt*16 + quad*4 + r;
                size_t o = (size_t)(i0 + row)*PDIM + col;
                float v = out[o] + acc[mt][nt][r];
                v = (v - mn)*rs*g + bb;
                out[o] = fmaxf(v, 0.f);
            }
        }
    }
}

extern "C" void kernel_launch(void* const* d_in, const int* in_sizes, int n_in,
                              void* d_out, int out_size, void* d_ws, size_t ws_size,
                              hipStream_t stream) {
    const float* pts   = (const float*)d_in[0];
    const int*   vc    = (const int*)d_in[1];
    const float* img   = (const float*)d_in[2];
    const float* l2i   = (const float*)d_in[3];
    const float* iaug  = (const float*)d_in[4];
    const float* laug  = (const float*)d_in[5];
    const float* conv  = (const float*)d_in[6];
    const float* gamma = (const float*)d_in[7];
    const float* beta  = (const float*)d_in[8];
    const float* mean  = (const float*)d_in[9];
    const float* var   = (const float*)d_in[10];
    float* out = (float*)d_out;

    char* ws = (char*)d_ws;
    int*          grid  = (int*)(ws + OFF_GRID);
    float*        imgt  = (float*)(ws + OFF_IMGT);
    unsigned int* descm = (unsigned int*)(ws + OFF_DESCM);
    uint2*        descw = (uint2*)(ws + OFF_DESCW);
    ushort4*      wp    = (ushort4*)(ws + OFF_WPACK);   // overlays descm AFTER k_fuse
    ushort4*      fuse4 = (ushort4*)(ws + OFF_FUSE);
    int*          cnt   = (int*)(ws + OFF_CNT);
    int2*         pairs = (int2*)(ws + OFF_PAIRS);
    const uint4*  fuse16 = (const uint4*)fuse4;
    const bf16x8* wpb    = (const bf16x8*)wp;

    hipMemsetAsync(grid, 0xFF, (size_t)NCELLS*4, stream);
    hipMemsetAsync(cnt, 0, 32*4, stream);
    hipMemsetAsync(d_out, 0, (size_t)out_size*4, stream);

    int blocksM = (MPTS + 255)/256;
    k_scatter<<<blocksM, 256, 0, stream>>>(vc, grid);
    k_transpose<<<(NCAM*CIMG*HF*WF + 255)/256, 256, 0, stream>>>(img, imgt);
    k_proj<<<blocksM, 256, 0, stream>>>(vc, l2i, iaug, laug, descm, descw);
    k_fuse<<<BPTS + BIMG, 256, 0, stream>>>((const float4*)pts, (const float4*)imgt,
                                            descm, descw, fuse4);
    k_wpack<<<(27*7*8*64 + 255)/256, 256, 0, stream>>>(conv, wp);   // after k_fuse (descm overlay)
    k_pairs<<<blocksM, 256, 0, stream>>>(vc, grid, cnt, pairs);
    k_nbr<<<dim3(PAIR_CAP/32, 26), 256, 0, stream>>>(pairs, cnt, fuse16, wpb, out);
    k_center<<<(MPTS + 31)/32, 256, 0, stream>>>(vc, grid, fuse16, wpb,
                                                 gamma, beta, mean, var, out);
}